// Round 1
// baseline (732.501 us; speedup 1.0000x reference)
//
#include <hip/hip_runtime.h>

typedef __bf16 bf16x8 __attribute__((ext_vector_type(8)));
typedef __bf16 bf16x4 __attribute__((ext_vector_type(4)));
typedef float  f32x4  __attribute__((ext_vector_type(4)));

#define MFMA16(A, B, C) __builtin_amdgcn_mfma_f32_16x16x32_bf16(A, B, C, 0, 0, 0)

// ---------------- elementwise fp32 -> bf16 ----------------
__global__ __launch_bounds__(256) void convert_f32_bf16(const float* __restrict__ src,
                                                        __bf16* __restrict__ dst) {
    size_t i = ((size_t)blockIdx.x * 256 + threadIdx.x) * 4;
    float4 v = *(const float4*)(src + i);
    bf16x4 o;
    o.x = (__bf16)v.x; o.y = (__bf16)v.y; o.z = (__bf16)v.z; o.w = (__bf16)v.w;
    *(bf16x4*)(dst + i) = o;
}

// ---------------- 2048x2048 fp32 -> bf16 transpose (W -> W^T rows=[n][k]) ----------------
__global__ __launch_bounds__(256) void transpose_conv(const float* __restrict__ src,
                                                      __bf16* __restrict__ dst) {
    __shared__ float t[32][33];
    int x0 = blockIdx.x * 32, y0 = blockIdx.y * 32;
    int tx = threadIdx.x, ty = threadIdx.y;   // 32x8
    for (int r = 0; r < 4; ++r)
        t[ty + 8 * r][tx] = src[(size_t)(y0 + ty + 8 * r) * 2048 + x0 + tx];
    __syncthreads();
    for (int r = 0; r < 4; ++r)
        dst[(size_t)(x0 + ty + 8 * r) * 2048 + y0 + tx] = (__bf16)t[tx][ty + 8 * r];
}

// ---------------- per-head V transpose: qkv[s][4096+h*128+d] -> vtb[h][d][s] ----------------
__global__ __launch_bounds__(256) void v_transpose(const __bf16* __restrict__ qkv,
                                                   __bf16* __restrict__ vtb) {
    __shared__ __bf16 t[32][33];
    int h = blockIdx.z;
    int s0 = blockIdx.x * 32, d0 = blockIdx.y * 32;
    int tx = threadIdx.x, ty = threadIdx.y;   // 32x8
    for (int r = 0; r < 4; ++r)
        t[ty + 8 * r][tx] = qkv[(size_t)(s0 + ty + 8 * r) * 6144 + 4096 + h * 128 + d0 + tx];
    __syncthreads();
    for (int r = 0; r < 4; ++r)
        vtb[(size_t)h * 128 * 4096 + (size_t)(d0 + ty + 8 * r) * 4096 + s0 + tx] = t[tx][ty + 8 * r];
}

// ---------------- fused RMSNorm + RoPE; writes head-major Q (pre-scaled by 1/sqrt(128)) and K ----------------
__global__ __launch_bounds__(64) void rmsrope(const __bf16* __restrict__ qkv,
                                              const float* __restrict__ qw,
                                              const float* __restrict__ kw,
                                              const int* __restrict__ pos_ids,
                                              __bf16* __restrict__ qhb,
                                              __bf16* __restrict__ khb) {
    int s = blockIdx.x;
    int slot = blockIdx.y;              // 0..31: 0-15 = q heads, 16-31 = k heads
    int lane = threadIdx.x;             // 0..63, handles dim pair (2*lane, 2*lane+1)
    bool isQ = slot < 16;
    int h = slot & 15;
    size_t base = (size_t)s * 6144 + (isQ ? 0 : 2048) + h * 128 + lane * 2;
    float x0 = (float)qkv[base], x1 = (float)qkv[base + 1];
    float ss = x0 * x0 + x1 * x1;
    for (int m = 1; m < 64; m <<= 1) ss += __shfl_xor(ss, m);
    float rr = rsqrtf(ss * (1.0f / 128.0f) + 1e-6f);
    const float* wp = isQ ? qw : kw;
    float n0 = x0 * rr * wp[lane * 2], n1 = x1 * rr * wp[lane * 2 + 1];
    float freq = powf(10000.0f, -(float)lane * (1.0f / 64.0f));
    float ang = (float)pos_ids[s] * freq;
    float sn, cs;
    sincosf(ang, &sn, &cs);
    float o0 = n0 * cs - n1 * sn;
    float o1 = n0 * sn + n1 * cs;
    if (isQ) { o0 *= 0.08838834764831845f; o1 *= 0.08838834764831845f; }  // fold 1/sqrt(128)
    __bf16* dst = (isQ ? qhb : khb) + (size_t)h * 4096 * 128 + (size_t)s * 128 + lane * 2;
    dst[0] = (__bf16)o0; dst[1] = (__bf16)o1;
}

// ---------------- generic bf16 MFMA GEMM: C[M,N] = A[M,K] * Bt[N,K]^T ----------------
// 128x128 block tile, 4 waves, each wave 64x64 (4x4 of 16x16x32 MFMA). BK=32.
template <bool F32OUT>
__global__ __launch_bounds__(256) void gemm_bt(const __bf16* __restrict__ A, int lda,
                                               const __bf16* __restrict__ Bt, int ldb,
                                               void* __restrict__ Cout, int ldc, int K) {
    __shared__ __bf16 as[128][40];   // +8 pad: 2-way bank aliasing only (free, m136)
    __shared__ __bf16 bs[128][40];
    const int m0 = blockIdx.x * 128, n0 = blockIdx.y * 128;
    const int t = threadIdx.x;
    const int lane = t & 63, w = t >> 6;
    const int wm = (w >> 1) * 64, wn = (w & 1) * 64;
    const int ln = lane & 15, quad = lane >> 4;
    f32x4 acc[4][4] = {};
    for (int k0 = 0; k0 < K; k0 += 32) {
        for (int c = 0; c < 2; ++c) {
            int chunk = t + c * 256;             // 512 chunks of 8 bf16
            int row = chunk >> 2, kc = chunk & 3;
            *(uint4*)&as[row][kc * 8] = *(const uint4*)&A[(size_t)(m0 + row) * lda + k0 + kc * 8];
            *(uint4*)&bs[row][kc * 8] = *(const uint4*)&Bt[(size_t)(n0 + row) * ldb + k0 + kc * 8];
        }
        __syncthreads();
        bf16x8 af[4], bfr[4];
        for (int i = 0; i < 4; ++i) af[i] = *(const bf16x8*)&as[wm + i * 16 + ln][quad * 8];
        for (int j = 0; j < 4; ++j) bfr[j] = *(const bf16x8*)&bs[wn + j * 16 + ln][quad * 8];
        for (int i = 0; i < 4; ++i)
            for (int j = 0; j < 4; ++j)
                acc[i][j] = MFMA16(af[i], bfr[j], acc[i][j]);
        __syncthreads();
    }
    // C/D layout: col = lane&15, row = quad*4 + r   [m89/m91 verified]
    for (int i = 0; i < 4; ++i)
        for (int j = 0; j < 4; ++j)
            for (int r = 0; r < 4; ++r) {
                int row = m0 + wm + i * 16 + quad * 4 + r;
                int col = n0 + wn + j * 16 + ln;
                if (F32OUT) ((float*)Cout)[(size_t)row * ldc + col] = acc[i][j][r];
                else        ((__bf16*)Cout)[(size_t)row * ldc + col] = (__bf16)acc[i][j][r];
            }
}

// ---------------- flash attention (non-causal), one block = (head, 64 q-rows) ----------------
// Q pre-scaled. BN=64 key blocks. P transits LDS for C-layout -> A-layout.
__global__ __launch_bounds__(256) void flash_attn(const __bf16* __restrict__ Q,
                                                  const __bf16* __restrict__ Kb,
                                                  const __bf16* __restrict__ Vt,
                                                  __bf16* __restrict__ ctx) {
    __shared__ __bf16 ks[64][136];    // keys x dim (also used to stage Q once)
    __shared__ __bf16 vs[128][72];    // dim x keys (from pre-transposed V)
    __shared__ __bf16 ps[4][16][72];  // per-wave P tile, q-row x key
    const int h = blockIdx.y;
    const int m0 = blockIdx.x * 64;
    const int t = threadIdx.x;
    const int lane = t & 63, w = t >> 6;
    const int ln = lane & 15, quad = lane >> 4;
    const __bf16* Qh = Q + (size_t)h * 4096 * 128;
    const __bf16* Kh = Kb + (size_t)h * 4096 * 128;
    const __bf16* Vh = Vt + (size_t)h * 128 * 4096;

    // stage Q tile (64x128), pull A-frags to registers for the whole block
    for (int i = 0; i < 4; ++i) {
        int chunk = t + i * 256;
        int row = chunk >> 4, c = chunk & 15;
        *(uint4*)&ks[row][c * 8] = *(const uint4*)&Qh[(size_t)(m0 + row) * 128 + c * 8];
    }
    __syncthreads();
    bf16x8 qf[4];
    for (int kk = 0; kk < 4; ++kk)
        qf[kk] = *(const bf16x8*)&ks[w * 16 + ln][kk * 32 + quad * 8];
    __syncthreads();

    f32x4 oacc[8] = {};
    float m_i[4], l_i[4];
    for (int r = 0; r < 4; ++r) { m_i[r] = -1e30f; l_i[r] = 0.f; }

    for (int kb = 0; kb < 64; ++kb) {
        for (int i = 0; i < 4; ++i) {   // stage K (64x128) and V^T (128x64)
            int chunk = t + i * 256;
            int row = chunk >> 4, c = chunk & 15;
            *(uint4*)&ks[row][c * 8] = *(const uint4*)&Kh[(size_t)(kb * 64 + row) * 128 + c * 8];
            int vrow = chunk >> 3, vc = chunk & 7;
            *(uint4*)&vs[vrow][vc * 8] = *(const uint4*)&Vh[(size_t)vrow * 4096 + kb * 64 + vc * 8];
        }
        __syncthreads();

        // S = Q * K^T  (per wave: 16 rows x 64 keys)
        f32x4 sacc[4] = {};
        for (int j = 0; j < 4; ++j)
            for (int kk = 0; kk < 4; ++kk) {
                bf16x8 kf = *(const bf16x8*)&ks[j * 16 + ln][kk * 32 + quad * 8];
                sacc[j] = MFMA16(qf[kk], kf, sacc[j]);
            }

        // online softmax; row r of this wave = quad*4 + r, replicated over 16 lanes
        float alpha[4], rs[4];
        for (int r = 0; r < 4; ++r) {
            float mx = fmaxf(fmaxf(sacc[0][r], sacc[1][r]), fmaxf(sacc[2][r], sacc[3][r]));
            for (int msk = 1; msk < 16; msk <<= 1) mx = fmaxf(mx, __shfl_xor(mx, msk));
            float mn = fmaxf(m_i[r], mx);
            alpha[r] = __expf(m_i[r] - mn);
            m_i[r] = mn;
            rs[r] = 0.f;
        }
        for (int j = 0; j < 4; ++j)
            for (int r = 0; r < 4; ++r) {
                float p = __expf(sacc[j][r] - m_i[r]);
                rs[r] += p;
                ps[w][quad * 4 + r][j * 16 + ln] = (__bf16)p;   // C-layout -> LDS
            }
        for (int r = 0; r < 4; ++r) {
            float s = rs[r];
            for (int msk = 1; msk < 16; msk <<= 1) s += __shfl_xor(s, msk);
            l_i[r] = l_i[r] * alpha[r] + s;
        }
        for (int t8 = 0; t8 < 8; ++t8)
            for (int r = 0; r < 4; ++r) oacc[t8][r] *= alpha[r];
        __syncthreads();

        // O += P * V   (A-frags of P from LDS)
        bf16x8 pf[2];
        pf[0] = *(const bf16x8*)&ps[w][ln][quad * 8];
        pf[1] = *(const bf16x8*)&ps[w][ln][32 + quad * 8];
        for (int t8 = 0; t8 < 8; ++t8)
            for (int kk = 0; kk < 2; ++kk) {
                bf16x8 vf = *(const bf16x8*)&vs[t8 * 16 + ln][kk * 32 + quad * 8];
                oacc[t8] = MFMA16(pf[kk], vf, oacc[t8]);
            }
        __syncthreads();
    }

    for (int t8 = 0; t8 < 8; ++t8)
        for (int r = 0; r < 4; ++r) {
            int row = m0 + w * 16 + quad * 4 + r;
            int col = h * 128 + t8 * 16 + ln;
            ctx[(size_t)row * 2048 + col] = (__bf16)(oacc[t8][r] / l_i[r]);
        }
}

// ---------------- launch ----------------
extern "C" void kernel_launch(void* const* d_in, const int* in_sizes, int n_in,
                              void* d_out, int out_size, void* d_ws, size_t ws_size,
                              hipStream_t stream) {
    const float* hs  = (const float*)d_in[0];
    const int*   pos = (const int*)d_in[1];
    const float* wq  = (const float*)d_in[2];
    const float* wk  = (const float*)d_in[3];
    const float* wv  = (const float*)d_in[4];
    const float* wo  = (const float*)d_in[5];
    const float* qw  = (const float*)d_in[6];
    const float* kw  = (const float*)d_in[7];

    // workspace layout (104 MB total), phase-overlapped:
    //  [0,16M):   xb (conv_x -> gemm1), then qhb (rmsrope -> flash)
    //  [16,40M):  wqkvtb (transpose -> gemm1), then khb@16M + vtb@32M
    //  [48,96M):  qkvb (gemm1 -> rmsrope/vtrans), then ctxb@48M (flash -> gemm2)
    //  [96,104M): wotb (transpose -> gemm2)
    char* ws = (char*)d_ws;
    const size_t MB = 1024 * 1024;
    __bf16* xb     = (__bf16*)(ws + 0);
    __bf16* wqkvtb = (__bf16*)(ws + 16 * MB);
    __bf16* qhb    = (__bf16*)(ws + 0);
    __bf16* khb    = (__bf16*)(ws + 16 * MB);
    __bf16* vtb    = (__bf16*)(ws + 32 * MB);
    __bf16* qkvb   = (__bf16*)(ws + 48 * MB);
    __bf16* ctxb   = (__bf16*)(ws + 48 * MB);
    __bf16* wotb   = (__bf16*)(ws + 96 * MB);

    dim3 tb(32, 8);
    convert_f32_bf16<<<8192, 256, 0, stream>>>(hs, xb);
    transpose_conv<<<dim3(64, 64), tb, 0, stream>>>(wq, wqkvtb);
    transpose_conv<<<dim3(64, 64), tb, 0, stream>>>(wk, wqkvtb + (size_t)2048 * 2048);
    transpose_conv<<<dim3(64, 64), tb, 0, stream>>>(wv, wqkvtb + (size_t)2 * 2048 * 2048);
    transpose_conv<<<dim3(64, 64), tb, 0, stream>>>(wo, wotb);

    // QKV projection: [4096,2048] x [2048,6144]
    gemm_bt<false><<<dim3(32, 48), 256, 0, stream>>>(xb, 2048, wqkvtb, 2048, qkvb, 6144, 2048);

    rmsrope<<<dim3(4096, 32), 64, 0, stream>>>(qkvb, qw, kw, pos, qhb, khb);
    v_transpose<<<dim3(128, 4, 16), tb, 0, stream>>>(qkvb, vtb);

    flash_attn<<<dim3(64, 16), 256, 0, stream>>>(qhb, khb, vtb, ctxb);

    // output projection: [4096,2048] x [2048,2048] -> fp32 out
    gemm_bt<true><<<dim3(32, 16), 256, 0, stream>>>(ctxb, 2048, wotb, 2048, d_out, 2048, 2048);
}

// Round 2
// 647.328 us; speedup vs baseline: 1.1316x; 1.1316x over previous
//
#include <hip/hip_runtime.h>

typedef __bf16 bf16x8 __attribute__((ext_vector_type(8)));
typedef __bf16 bf16x4 __attribute__((ext_vector_type(4)));
typedef float  f32x4  __attribute__((ext_vector_type(4)));

#define MFMA16(A, B, C) __builtin_amdgcn_mfma_f32_16x16x32_bf16(A, B, C, 0, 0, 0)

#if __has_builtin(__builtin_amdgcn_exp2f)
#define EXP2F(x) __builtin_amdgcn_exp2f(x)
#else
#define EXP2F(x) exp2f(x)
#endif

// ---------------- elementwise fp32 -> bf16 ----------------
__global__ __launch_bounds__(256) void convert_f32_bf16(const float* __restrict__ src,
                                                        __bf16* __restrict__ dst) {
    size_t i = ((size_t)blockIdx.x * 256 + threadIdx.x) * 4;
    float4 v = *(const float4*)(src + i);
    bf16x4 o;
    o.x = (__bf16)v.x; o.y = (__bf16)v.y; o.z = (__bf16)v.z; o.w = (__bf16)v.w;
    *(bf16x4*)(dst + i) = o;
}

// ---------------- 2048x2048 fp32 -> bf16 transpose (W -> W^T rows=[n][k]) ----------------
__global__ __launch_bounds__(256) void transpose_conv(const float* __restrict__ src,
                                                      __bf16* __restrict__ dst) {
    __shared__ float t[32][33];
    int x0 = blockIdx.x * 32, y0 = blockIdx.y * 32;
    int tx = threadIdx.x, ty = threadIdx.y;   // 32x8
    for (int r = 0; r < 4; ++r)
        t[ty + 8 * r][tx] = src[(size_t)(y0 + ty + 8 * r) * 2048 + x0 + tx];
    __syncthreads();
    for (int r = 0; r < 4; ++r)
        dst[(size_t)(x0 + ty + 8 * r) * 2048 + y0 + tx] = (__bf16)t[tx][ty + 8 * r];
}

// ---------------- per-head V transpose: qkv[s][4096+h*128+d] -> vtb[h][d][s] ----------------
__global__ __launch_bounds__(256) void v_transpose(const __bf16* __restrict__ qkv,
                                                   __bf16* __restrict__ vtb) {
    __shared__ __bf16 t[32][33];
    int h = blockIdx.z;
    int s0 = blockIdx.x * 32, d0 = blockIdx.y * 32;
    int tx = threadIdx.x, ty = threadIdx.y;   // 32x8
    for (int r = 0; r < 4; ++r)
        t[ty + 8 * r][tx] = qkv[(size_t)(s0 + ty + 8 * r) * 6144 + 4096 + h * 128 + d0 + tx];
    __syncthreads();
    for (int r = 0; r < 4; ++r)
        vtb[(size_t)h * 128 * 4096 + (size_t)(d0 + ty + 8 * r) * 4096 + s0 + tx] = t[tx][ty + 8 * r];
}

// ---------------- fused RMSNorm + RoPE; head-major Q (pre-scaled by log2e/sqrt(128)) and K ----------------
__global__ __launch_bounds__(64) void rmsrope(const __bf16* __restrict__ qkv,
                                              const float* __restrict__ qw,
                                              const float* __restrict__ kw,
                                              const int* __restrict__ pos_ids,
                                              __bf16* __restrict__ qhb,
                                              __bf16* __restrict__ khb) {
    int s = blockIdx.x;
    int slot = blockIdx.y;              // 0..31: 0-15 = q heads, 16-31 = k heads
    int lane = threadIdx.x;             // 0..63, handles dim pair (2*lane, 2*lane+1)
    bool isQ = slot < 16;
    int h = slot & 15;
    size_t base = (size_t)s * 6144 + (isQ ? 0 : 2048) + h * 128 + lane * 2;
    float x0 = (float)qkv[base], x1 = (float)qkv[base + 1];
    float ss = x0 * x0 + x1 * x1;
    for (int m = 1; m < 64; m <<= 1) ss += __shfl_xor(ss, m);
    float rr = rsqrtf(ss * (1.0f / 128.0f) + 1e-6f);
    const float* wp = isQ ? qw : kw;
    float n0 = x0 * rr * wp[lane * 2], n1 = x1 * rr * wp[lane * 2 + 1];
    float freq = powf(10000.0f, -(float)lane * (1.0f / 64.0f));
    float ang = (float)pos_ids[s] * freq;
    float sn, cs;
    sincosf(ang, &sn, &cs);
    float o0 = n0 * cs - n1 * sn;
    float o1 = n0 * sn + n1 * cs;
    // fold (1/sqrt(128)) * log2(e) into Q so scores are in exp2 domain
    if (isQ) { o0 *= 0.12751744416196178f; o1 *= 0.12751744416196178f; }
    __bf16* dst = (isQ ? qhb : khb) + (size_t)h * 4096 * 128 + (size_t)s * 128 + lane * 2;
    dst[0] = (__bf16)o0; dst[1] = (__bf16)o1;
}

// ---------------- generic bf16 MFMA GEMM: C[M,N] = A[M,K] * Bt[N,K]^T ----------------
// 128x128 tile, 4 waves, 4x4 16x16x32 MFMA per wave. global_load_lds width-16 staging (m97).
template <bool F32OUT>
__global__ __launch_bounds__(256) void gemm_bt(const __bf16* __restrict__ A, int lda,
                                               const __bf16* __restrict__ Bt, int ldb,
                                               void* __restrict__ Cout, int ldc, int K) {
    __shared__ __bf16 as[128][32];   // unpadded: required by global_load_lds contiguity
    __shared__ __bf16 bs[128][32];
    const int m0 = blockIdx.x * 128, n0 = blockIdx.y * 128;
    const int t = threadIdx.x;
    const int lane = t & 63, w = t >> 6;
    const int wm = (w >> 1) * 64, wn = (w & 1) * 64;
    const int ln = lane & 15, quad = lane >> 4;
    auto as3 = (__attribute__((address_space(3))) uint32_t*)as;
    auto bs3 = (__attribute__((address_space(3))) uint32_t*)bs;
    f32x4 acc[4][4] = {};
    for (int k0 = 0; k0 < K; k0 += 32) {
        for (int c = 0; c < 2; ++c) {
            int g = c * 256 + t;               // chunk id: 512 chunks of 16B per tile
            int row = g >> 2, kc = g & 3;
            const __bf16* ga = &A[(size_t)(m0 + row) * lda + k0 + kc * 8];
            const __bf16* gb = &Bt[(size_t)(n0 + row) * ldb + k0 + kc * 8];
            __builtin_amdgcn_global_load_lds((const __attribute__((address_space(1))) uint32_t*)ga,
                                             as3 + c * 1024 + w * 256, 16, 0, 0);
            __builtin_amdgcn_global_load_lds((const __attribute__((address_space(1))) uint32_t*)gb,
                                             bs3 + c * 1024 + w * 256, 16, 0, 0);
        }
        __syncthreads();
        bf16x8 af[4], bfr[4];
        for (int i = 0; i < 4; ++i) af[i] = *(const bf16x8*)&as[wm + i * 16 + ln][quad * 8];
        for (int j = 0; j < 4; ++j) bfr[j] = *(const bf16x8*)&bs[wn + j * 16 + ln][quad * 8];
        for (int i = 0; i < 4; ++i)
            for (int j = 0; j < 4; ++j)
                acc[i][j] = MFMA16(af[i], bfr[j], acc[i][j]);
        __syncthreads();
    }
    // C/D layout: col = lane&15, row = quad*4 + r   [m89/m91 verified]
    for (int i = 0; i < 4; ++i)
        for (int j = 0; j < 4; ++j)
            for (int r = 0; r < 4; ++r) {
                int row = m0 + wm + i * 16 + quad * 4 + r;
                int col = n0 + wn + j * 16 + ln;
                if (F32OUT) ((float*)Cout)[(size_t)row * ldc + col] = acc[i][j][r];
                else        ((__bf16*)Cout)[(size_t)row * ldc + col] = (__bf16)acc[i][j][r];
            }
}

// ---------------- flash attention, fixed-max softmax, BM=128 ----------------
// Valid because q/k are RMS-normalized (unit norm weights): |s*log2e| <= sqrt(128)*log2e = 16.33 < 16.5.
// p = exp2(s~ - 16.5) is exact softmax after final division; no running max/rescale needed.
__global__ __launch_bounds__(256) void flash_attn(const __bf16* __restrict__ Q,
                                                  const __bf16* __restrict__ Kb,
                                                  const __bf16* __restrict__ Vt,
                                                  __bf16* __restrict__ ctx) {
    __shared__ __bf16 ks[64][136];    // keys x dim; row stride 68 words == 4 mod 32: uniform banks
    __shared__ __bf16 vs[128][72];    // dim x keys; stride 36 words == 4 mod 32
    __shared__ __bf16 ps[4][32][68];  // per-wave P; stride 34 words: quads land in disjoint windows
    const int h = blockIdx.y;
    const int m0 = blockIdx.x * 128;
    const int t = threadIdx.x;
    const int lane = t & 63, w = t >> 6;
    const int ln = lane & 15, quad = lane >> 4;
    const __bf16* Qh = Q + (size_t)h * 4096 * 128;
    const __bf16* Kh = Kb + (size_t)h * 4096 * 128;
    const __bf16* Vh = Vt + (size_t)h * 128 * 4096;

    // stage Q (two 64-row halves through ks), keep A-frags in registers
    bf16x8 qf[2][4];
    for (int half = 0; half < 2; ++half) {
        for (int i = 0; i < 4; ++i) {
            int chunk = t + i * 256;
            int row = chunk >> 4, cc = chunk & 15;
            *(uint4*)&ks[row][cc * 8] =
                *(const uint4*)&Qh[(size_t)(m0 + half * 64 + row) * 128 + cc * 8];
        }
        __syncthreads();
        for (int kk = 0; kk < 4; ++kk)
            qf[half][kk] = *(const bf16x8*)&ks[w * 16 + ln][kk * 32 + quad * 8];
        __syncthreads();
    }

    f32x4 oacc[2][8] = {};
    float rs[2][4] = {};              // per-lane partial sum of p (no rescale ever needed)

    for (int kb = 0; kb < 64; ++kb) {
        for (int i = 0; i < 4; ++i) {   // stage K (64x128) and V^T (128x64)
            int chunk = t + i * 256;
            int row = chunk >> 4, cc = chunk & 15;
            *(uint4*)&ks[row][cc * 8] =
                *(const uint4*)&Kh[(size_t)(kb * 64 + row) * 128 + cc * 8];
            int vrow = chunk >> 3, vc = chunk & 7;
            *(uint4*)&vs[vrow][vc * 8] =
                *(const uint4*)&Vh[(size_t)vrow * 4096 + kb * 64 + vc * 8];
        }
        __syncthreads();

        // S~ = Q*K^T - 16.5 (bias via MFMA C-init); each kf frag reused for both row-tiles
        f32x4 sacc[2][4];
        const f32x4 mC = {-16.5f, -16.5f, -16.5f, -16.5f};
        for (int i = 0; i < 2; ++i)
            for (int j = 0; j < 4; ++j) sacc[i][j] = mC;
        for (int j = 0; j < 4; ++j)
            for (int kk = 0; kk < 4; ++kk) {
                bf16x8 kf = *(const bf16x8*)&ks[j * 16 + ln][kk * 32 + quad * 8];
                sacc[0][j] = MFMA16(qf[0][kk], kf, sacc[0][j]);
                sacc[1][j] = MFMA16(qf[1][kk], kf, sacc[1][j]);
            }

        // p = exp2(s~); accumulate per-lane partial l; C-layout -> LDS (wave-private, no barrier)
        for (int i = 0; i < 2; ++i)
            for (int j = 0; j < 4; ++j)
                for (int r = 0; r < 4; ++r) {
                    float p = EXP2F(sacc[i][j][r]);
                    rs[i][r] += p;
                    ps[w][i * 16 + quad * 4 + r][j * 16 + ln] = (__bf16)p;
                }

        // O += P*V; each vf frag reused for both row-tiles
        bf16x8 pf[2][2];
        for (int i = 0; i < 2; ++i)
            for (int kk = 0; kk < 2; ++kk)
                pf[i][kk] = *(const bf16x8*)&ps[w][i * 16 + ln][kk * 32 + quad * 8];
        for (int t8 = 0; t8 < 8; ++t8)
            for (int kk = 0; kk < 2; ++kk) {
                bf16x8 vf = *(const bf16x8*)&vs[t8 * 16 + ln][kk * 32 + quad * 8];
                oacc[0][t8] = MFMA16(pf[0][kk], vf, oacc[0][t8]);
                oacc[1][t8] = MFMA16(pf[1][kk], vf, oacc[1][t8]);
            }
        __syncthreads();
    }

    // reduce l across the 16 lanes of each quad-row, once
    float inv[2][4];
    for (int i = 0; i < 2; ++i)
        for (int r = 0; r < 4; ++r) {
            float s = rs[i][r];
            for (int msk = 1; msk < 16; msk <<= 1) s += __shfl_xor(s, msk);
            inv[i][r] = 1.0f / s;
        }
    for (int i = 0; i < 2; ++i)
        for (int t8 = 0; t8 < 8; ++t8)
            for (int r = 0; r < 4; ++r) {
                int row = m0 + i * 64 + w * 16 + quad * 4 + r;
                int col = h * 128 + t8 * 16 + ln;
                ctx[(size_t)row * 2048 + col] = (__bf16)(oacc[i][t8][r] * inv[i][r]);
            }
}

// ---------------- launch ----------------
extern "C" void kernel_launch(void* const* d_in, const int* in_sizes, int n_in,
                              void* d_out, int out_size, void* d_ws, size_t ws_size,
                              hipStream_t stream) {
    const float* hs  = (const float*)d_in[0];
    const int*   pos = (const int*)d_in[1];
    const float* wq  = (const float*)d_in[2];
    const float* wk  = (const float*)d_in[3];
    const float* wv  = (const float*)d_in[4];
    const float* wo  = (const float*)d_in[5];
    const float* qw  = (const float*)d_in[6];
    const float* kw  = (const float*)d_in[7];

    char* ws = (char*)d_ws;
    const size_t MB = 1024 * 1024;
    __bf16* xb     = (__bf16*)(ws + 0);
    __bf16* wqkvtb = (__bf16*)(ws + 16 * MB);
    __bf16* qhb    = (__bf16*)(ws + 0);
    __bf16* khb    = (__bf16*)(ws + 16 * MB);
    __bf16* vtb    = (__bf16*)(ws + 32 * MB);
    __bf16* qkvb   = (__bf16*)(ws + 48 * MB);
    __bf16* ctxb   = (__bf16*)(ws + 48 * MB);
    __bf16* wotb   = (__bf16*)(ws + 96 * MB);

    dim3 tb(32, 8);
    convert_f32_bf16<<<8192, 256, 0, stream>>>(hs, xb);
    transpose_conv<<<dim3(64, 64), tb, 0, stream>>>(wq, wqkvtb);
    transpose_conv<<<dim3(64, 64), tb, 0, stream>>>(wk, wqkvtb + (size_t)2048 * 2048);
    transpose_conv<<<dim3(64, 64), tb, 0, stream>>>(wv, wqkvtb + (size_t)2 * 2048 * 2048);
    transpose_conv<<<dim3(64, 64), tb, 0, stream>>>(wo, wotb);

    // QKV projection: [4096,2048] x [2048,6144]
    gemm_bt<false><<<dim3(32, 48), 256, 0, stream>>>(xb, 2048, wqkvtb, 2048, qkvb, 6144, 2048);

    rmsrope<<<dim3(4096, 32), 64, 0, stream>>>(qkvb, qw, kw, pos, qhb, khb);
    v_transpose<<<dim3(128, 4, 16), tb, 0, stream>>>(qkvb, vtb);

    flash_attn<<<dim3(32, 16), 256, 0, stream>>>(qhb, khb, vtb, ctxb);

    // output projection: [4096,2048] x [2048,2048] -> fp32 out
    gemm_bt<true><<<dim3(32, 16), 256, 0, stream>>>(ctxb, 2048, wotb, 2048, d_out, 2048, 2048);
}